// Round 1
// baseline (437.774 us; speedup 1.0000x reference)
//
#include <hip/hip_runtime.h>
#include <hip/hip_bf16.h>

// Problem constants (B=4, S=4096, D=4096, r=4, COFF=2, HD=512)
#define D_DIM 4096
#define OD    1024          // COFF*HD combined projection width
#define M_TOT 16384         // B*S
#define N_TOT 2048          // 2*OD (kv/gate interleaved)
#define BM 128
#define BN 128
#define BK 64

typedef __attribute__((ext_vector_type(8))) short          bf16x8;
typedef __attribute__((ext_vector_type(8))) unsigned short u16x8;
typedef __attribute__((ext_vector_type(4))) float          f32x4;

__device__ __forceinline__ unsigned short f2bf(float f) {
    // round-to-nearest-even fp32 -> bf16 (inputs are normal values)
    unsigned int u = __float_as_uint(f);
    u = (u + 0x7fffu + ((u >> 16) & 1u)) >> 16;
    return (unsigned short)u;
}

__device__ __forceinline__ float sigm(float x) {
    return 1.0f / (1.0f + __expf(-x));
}

// ---- prep: interleave wkv/wgate rows into combined bf16 weight [2048][4096]
__global__ void prep_weights(const float* __restrict__ wkv,
                             const float* __restrict__ wgate,
                             unsigned short* __restrict__ Wc) {
    int t  = blockIdx.x * 256 + threadIdx.x;   // 2048 * 512 threads
    int n  = t >> 9;                           // combined row: o = n>>1, gate = n&1
    int k8 = t & 511;                          // 8-element chunk in row
    const float* src = (n & 1) ? wgate : wkv;
    const float4* s4 = (const float4*)(src + (size_t)(n >> 1) * D_DIM + k8 * 8);
    float4 a = s4[0], b = s4[1];
    u16x8 o;
    o[0] = f2bf(a.x); o[1] = f2bf(a.y); o[2] = f2bf(a.z); o[3] = f2bf(a.w);
    o[4] = f2bf(b.x); o[5] = f2bf(b.y); o[6] = f2bf(b.z); o[7] = f2bf(b.w);
    *(u16x8*)(Wc + (size_t)n * D_DIM + k8 * 8) = o;
}

// ---- prep: x fp32 -> bf16
__global__ void prep_x(const float* __restrict__ x, unsigned short* __restrict__ xb) {
    size_t t = (size_t)blockIdx.x * 256 + threadIdx.x;  // 8,388,608 threads * 8 elems
    const float4* s = (const float4*)(x + t * 8);
    float4 a = s[0], b = s[1];
    u16x8 o;
    o[0] = f2bf(a.x); o[1] = f2bf(a.y); o[2] = f2bf(a.z); o[3] = f2bf(a.w);
    o[4] = f2bf(b.x); o[5] = f2bf(b.y); o[6] = f2bf(b.z); o[7] = f2bf(b.w);
    *(u16x8*)(xb + t * 8) = o;
}

// ---- prep: ape mean over the 4 window positions (ape added after gating, then meaned)
__global__ void prep_ape(const float* __restrict__ ape, float* __restrict__ am) {
    int t = blockIdx.x * 256 + threadIdx.x;
    if (t < OD)
        am[t] = 0.25f * (ape[t] + ape[OD + t] + ape[2 * OD + t] + ape[3 * OD + t]);
}

// ---- main fused GEMM: C = x @ Wc^T, gate, +ape, window-mean, write pooled to d_out
// A_BF16: A source is pre-converted bf16 (preferred) or raw fp32 (ws fallback).
template <bool A_BF16>
__global__ __launch_bounds__(256)
void gemm_fused(const void* __restrict__ Aptr,
                const unsigned short* __restrict__ Wc,
                const float* __restrict__ ape_mean,
                float* __restrict__ out_pooled) {
    __shared__ __align__(16) unsigned short As[BM * BK];
    __shared__ __align__(16) unsigned short Bs[BN * BK];

    const int tid  = threadIdx.x;
    const int lane = tid & 63;
    const int wave = tid >> 6;           // 4 waves, 2x2 over the 128x128 tile
    const int wr   = wave >> 1;
    const int wc   = wave & 1;
    const int n0   = blockIdx.x * BN;    // combined-column tile
    const int m0   = blockIdx.y * BM;    // row (b*s) tile
    const int h    = lane & 15;
    const int q    = lane >> 4;

    f32x4 acc[4][4];
    const f32x4 z = {0.f, 0.f, 0.f, 0.f};
#pragma unroll
    for (int i = 0; i < 4; ++i)
#pragma unroll
        for (int j = 0; j < 4; ++j) acc[i][j] = z;

    for (int kt = 0; kt < D_DIM; kt += BK) {
        // stage A tile (128x64 bf16), XOR-swizzled rows (row stride = 128B)
#pragma unroll
        for (int i = 0; i < 4; ++i) {
            int chunk = tid + i * 256;       // 1024 chunks of 8 bf16
            int row   = chunk >> 3;
            int c8    = chunk & 7;
            int dst   = (row * BK + c8 * 8) ^ ((row & 7) << 3);
            if constexpr (A_BF16) {
                const u16x8* s = (const u16x8*)((const unsigned short*)Aptr +
                                                (size_t)(m0 + row) * D_DIM + kt + c8 * 8);
                *(u16x8*)&As[dst] = *s;
            } else {
                const float4* s = (const float4*)((const float*)Aptr +
                                                  (size_t)(m0 + row) * D_DIM + kt + c8 * 8);
                float4 a = s[0], b = s[1];
                u16x8 o;
                o[0] = f2bf(a.x); o[1] = f2bf(a.y); o[2] = f2bf(a.z); o[3] = f2bf(a.w);
                o[4] = f2bf(b.x); o[5] = f2bf(b.y); o[6] = f2bf(b.z); o[7] = f2bf(b.w);
                *(u16x8*)&As[dst] = o;
            }
        }
        // stage B tile (128x64 bf16 from interleaved weights)
#pragma unroll
        for (int i = 0; i < 4; ++i) {
            int chunk = tid + i * 256;
            int row   = chunk >> 3;
            int c8    = chunk & 7;
            int dst   = (row * BK + c8 * 8) ^ ((row & 7) << 3);
            const u16x8* s = (const u16x8*)(Wc + (size_t)(n0 + row) * D_DIM + kt + c8 * 8);
            *(u16x8*)&Bs[dst] = *s;
        }
        __syncthreads();

#pragma unroll
        for (int ks = 0; ks < 2; ++ks) {
            const int kb = ks * 32 + q * 8;
            bf16x8 af[4], bfr[4];
#pragma unroll
            for (int am = 0; am < 4; ++am) {
                int row = wr * 64 + am * 16 + h;
                af[am] = *(const bf16x8*)&As[(row * BK + kb) ^ ((row & 7) << 3)];
            }
#pragma unroll
            for (int bn = 0; bn < 4; ++bn) {
                int row = wc * 64 + bn * 16 + h;
                bfr[bn] = *(const bf16x8*)&Bs[(row * BK + kb) ^ ((row & 7) << 3)];
            }
#pragma unroll
            for (int am = 0; am < 4; ++am)
#pragma unroll
                for (int bn = 0; bn < 4; ++bn)
                    acc[am][bn] = __builtin_amdgcn_mfma_f32_16x16x32_bf16(
                        af[am], bfr[bn], acc[am][bn], 0, 0, 0);
        }
        __syncthreads();
    }

    // Epilogue: even combined-columns hold kv, odd hold gate logits (adjacent lanes).
    // Each lane's 4 acc regs are rows (q*4 .. q*4+3) == exactly one r=4 pooling window.
    const bool is_kv = ((h & 1) == 0);
#pragma unroll
    for (int am = 0; am < 4; ++am) {
        const int mbase = m0 + wr * 64 + am * 16 + q * 4;  // multiple of 4
        const int wglob = mbase >> 2;                      // b*1024 + s/4
#pragma unroll
        for (int bn = 0; bn < 4; ++bn) {
            f32x4 kv = acc[am][bn];
            float g0 = __shfl_xor(kv[0], 1);
            float g1 = __shfl_xor(kv[1], 1);
            float g2 = __shfl_xor(kv[2], 1);
            float g3 = __shfl_xor(kv[3], 1);
            if (is_kv) {
                float s = kv[0] * sigm(g0) + kv[1] * sigm(g1) +
                          kv[2] * sigm(g2) + kv[3] * sigm(g3);
                int n = n0 + wc * 64 + bn * 16 + h;   // even
                int o = n >> 1;
                // pooled layout [b][w][c*512+h] flattens to the OUTPUT layout exactly
                out_pooled[(size_t)wglob * OD + o] = 0.25f * s + ape_mean[o];
            }
        }
    }
}

// ---- in-place RMSNorm over head_dim=512 per token (8192 tokens)
__global__ void rmsnorm_inplace(float* __restrict__ out, const float* __restrict__ nw) {
    int token = blockIdx.x * 4 + (threadIdx.x >> 6);   // one wave per token
    int lane  = threadIdx.x & 63;
    float4* p = (float4*)(out + (size_t)token * 512);
    float4 v0 = p[lane * 2], v1 = p[lane * 2 + 1];
    float ss = v0.x * v0.x + v0.y * v0.y + v0.z * v0.z + v0.w * v0.w +
               v1.x * v1.x + v1.y * v1.y + v1.z * v1.z + v1.w * v1.w;
#pragma unroll
    for (int off = 32; off > 0; off >>= 1) ss += __shfl_xor(ss, off);
    float rs = rsqrtf(ss * (1.0f / 512.0f) + 1e-6f);
    const float4* w4 = (const float4*)nw;
    float4 w0 = w4[lane * 2], w1 = w4[lane * 2 + 1];
    float4 r0, r1;
    r0.x = v0.x * rs * w0.x; r0.y = v0.y * rs * w0.y;
    r0.z = v0.z * rs * w0.z; r0.w = v0.w * rs * w0.w;
    r1.x = v1.x * rs * w1.x; r1.y = v1.y * rs * w1.y;
    r1.z = v1.z * rs * w1.z; r1.w = v1.w * rs * w1.w;
    p[lane * 2]     = r0;
    p[lane * 2 + 1] = r1;
}

extern "C" void kernel_launch(void* const* d_in, const int* in_sizes, int n_in,
                              void* d_out, int out_size, void* d_ws, size_t ws_size,
                              hipStream_t stream) {
    const float* x     = (const float*)d_in[0];
    const float* wkv   = (const float*)d_in[1];
    const float* wgate = (const float*)d_in[2];
    const float* ape   = (const float*)d_in[3];
    const float* normw = (const float*)d_in[4];
    float* out = (float*)d_out;

    // ws layout: Wc bf16 [2048][4096] (16 MiB) | ape_mean (64 KiB slot) | xb bf16 (128 MiB)
    unsigned short* Wc  = (unsigned short*)d_ws;
    float* ape_mean     = (float*)((char*)d_ws + (size_t)16 * 1024 * 1024);
    unsigned short* xb  = (unsigned short*)((char*)d_ws + (size_t)16 * 1024 * 1024 + 65536);
    const size_t need_xb = (size_t)16 * 1024 * 1024 + 65536 + (size_t)M_TOT * D_DIM * 2;
    const bool use_xb = (ws_size >= need_xb);

    prep_weights<<<4096, 256, 0, stream>>>(wkv, wgate, Wc);
    prep_ape<<<4, 256, 0, stream>>>(ape, ape_mean);

    if (use_xb) {
        prep_x<<<32768, 256, 0, stream>>>(x, xb);
        gemm_fused<true><<<dim3(N_TOT / BN, M_TOT / BM), 256, 0, stream>>>(
            xb, Wc, ape_mean, out);
    } else {
        gemm_fused<false><<<dim3(N_TOT / BN, M_TOT / BM), 256, 0, stream>>>(
            x, Wc, ape_mean, out);
    }

    rmsnorm_inplace<<<2048, 256, 0, stream>>>(out, normw);
}